// Round 4
// baseline (299.085 us; speedup 1.0000x reference)
//
#include <hip/hip_runtime.h>

// SoftDepthShader: softmax depth blend, N=8 H=256 W=256 K=50 (524288 pixels).
// 262 MB unique input (p2f is int32 on device), ~2 MB out. FETCH_SIZE ~153 MB
// (L3 serves the rest across replays). All R3..R6 structures pinned at
// 110-123 us = latency/duty-cycle-bound (R3: 1.2 KB/CU outstanding matches
// 2.4 TB/s via Little's law; R6's delivery windows hit ~4 TB/s instantaneous
// but vmcnt(0)-after-compute serialized C + D_full per iteration: 7.7 us/iter).
//
// R7 = R6 + counted vmcnt (T3+T4 done right):
//   - Per-wave glds count nw (waves 0-2: 10, waves 3-7: 9 of the 75 1KB steps).
//   - Loop: stage(i+1) FIRST, then wait vmcnt leaving {store(i-1), stage(i+1)}
//     outstanding = nw+1 (iter0: nw; last: 1). vmcnt retires in order, so
//     tile i's loads are provably drained; the fresh prefetch stays in flight
//     through the whole compute. Steady state = max(C, D) + 2 barriers.
//   - Raw s_barrier (no implicit drain) + sched_barrier fences.
//   - __fdividef for sigmoid + final blend (kills ~7-inst IEEE div sequences).
// Staging and compute bodies are R6's harness-proven code, unchanged.

constexpr int THREADS  = 512;
constexpr int WAVES    = THREADS / 64;    // 8
constexpr int TILE_PX  = 128;
constexpr int PX_B     = 200;             // bytes per pixel per array
constexpr int ARR_B    = TILE_PX * PX_B;  // 25600 = 25 x 1024
constexpr int BUF_B    = 3 * ARR_B;       // 76800
constexpr int STEPS    = BUF_B / 1024;    // 75 wave-steps per tile
constexpr int TILES_PB = 16;              // tiles per block

constexpr float INV_SIGMA  = 1e4f;        // 1/sigma
constexpr float INVG       = 1e4f;        // 1/gamma
constexpr float ZFAR       = 100.0f;
constexpr float ZRANGE     = 99.0f;       // zfar - znear
constexpr float INV_ZRANGE = 1.0f / 99.0f;
constexpr float EPS        = 1e-10f;

#define GLDS16(gp, lp) __builtin_amdgcn_global_load_lds(                     \
    (const __attribute__((address_space(1))) void*)(gp),                     \
    (__attribute__((address_space(3))) void*)(lp), 16, 0, 0)

#define VMWAIT(N) asm volatile("s_waitcnt vmcnt(" #N ")" ::: "memory")

// Harness-proven per-pixel pipeline (R5/R6), divisions -> __fdividef.
__device__ __forceinline__ void pixel_blend(
    const int2 fa, const int2 fb, const int2 fc, const int2 fd,
    const float2 za, const float2 zb, const float2 zc, const float2 zd,
    const float2 da, const float2 db, const float2 dc, const float2 dd,
    const bool tail_owner,
    float& m_out, float& s1_out, float& s2_out)
{
    const bool m0 = (fa.x >= 0),               m1 = (fa.y >= 0);
    const bool m2 = (fb.x >= 0),               m3 = (fb.y >= 0);
    const bool m4 = (fc.x >= 0),               m5 = (fc.y >= 0);
    const bool m6 = tail_owner && (fd.x >= 0), m7 = tail_owner && (fd.y >= 0);

    float zv[8], pv[8];
    zv[0] = m0 ? (ZFAR - za.x) * INV_ZRANGE : 0.0f;
    zv[1] = m1 ? (ZFAR - za.y) * INV_ZRANGE : 0.0f;
    zv[2] = m2 ? (ZFAR - zb.x) * INV_ZRANGE : 0.0f;
    zv[3] = m3 ? (ZFAR - zb.y) * INV_ZRANGE : 0.0f;
    zv[4] = m4 ? (ZFAR - zc.x) * INV_ZRANGE : 0.0f;
    zv[5] = m5 ? (ZFAR - zc.y) * INV_ZRANGE : 0.0f;
    zv[6] = m6 ? (ZFAR - zd.x) * INV_ZRANGE : 0.0f;
    zv[7] = m7 ? (ZFAR - zd.y) * INV_ZRANGE : 0.0f;
    pv[0] = m0 ? __fdividef(1.0f, 1.0f + __expf(da.x * INV_SIGMA)) : 0.0f;
    pv[1] = m1 ? __fdividef(1.0f, 1.0f + __expf(da.y * INV_SIGMA)) : 0.0f;
    pv[2] = m2 ? __fdividef(1.0f, 1.0f + __expf(db.x * INV_SIGMA)) : 0.0f;
    pv[3] = m3 ? __fdividef(1.0f, 1.0f + __expf(db.y * INV_SIGMA)) : 0.0f;
    pv[4] = m4 ? __fdividef(1.0f, 1.0f + __expf(dc.x * INV_SIGMA)) : 0.0f;
    pv[5] = m5 ? __fdividef(1.0f, 1.0f + __expf(dc.y * INV_SIGMA)) : 0.0f;
    pv[6] = m6 ? __fdividef(1.0f, 1.0f + __expf(dd.x * INV_SIGMA)) : 0.0f;
    pv[7] = m7 ? __fdividef(1.0f, 1.0f + __expf(dd.y * INV_SIGMA)) : 0.0f;

    float m = fmaxf(fmaxf(fmaxf(zv[0], zv[1]), fmaxf(zv[2], zv[3])),
                    fmaxf(fmaxf(zv[4], zv[5]), fmaxf(zv[6], zv[7])));
    m = fmaxf(m, __shfl_xor(m, 1));
    m = fmaxf(m, __shfl_xor(m, 2));
    m = fmaxf(m, __shfl_xor(m, 4));
    m = fmaxf(m, EPS);

    float S1a = 0.0f, S1b = 0.0f, S2a = 0.0f, S2b = 0.0f;
    #pragma unroll
    for (int j = 0; j < 8; j += 2) {
        const float w0 = pv[j]   * __expf((zv[j]   - m) * INVG);
        const float w1 = pv[j+1] * __expf((zv[j+1] - m) * INVG);
        S1a += w0;
        S1b += w1;
        S2a += w0 * (ZFAR - zv[j]   * ZRANGE);
        S2b += w1 * (ZFAR - zv[j+1] * ZRANGE);
    }
    float S1 = S1a + S1b;
    float S2 = S2a + S2b;
    S1 += __shfl_xor(S1, 1);  S1 += __shfl_xor(S1, 2);  S1 += __shfl_xor(S1, 4);
    S2 += __shfl_xor(S2, 1);  S2 += __shfl_xor(S2, 2);  S2 += __shfl_xor(S2, 4);

    m_out = m;  s1_out = S1;  s2_out = S2;
}

__global__ __launch_bounds__(THREADS, 2) void soft_depth_kernel(
    const float* __restrict__ zbuf,
    const float* __restrict__ dists,
    const int*   __restrict__ p2f,
    float*       __restrict__ out)
{
    __shared__ __align__(16) char smem[2 * BUF_B];   // 153,600 B

    const int t    = threadIdx.x;
    const int lane = t & 63;
    const int wid  = t >> 6;
    const int q    = t & 7;
    const int team = t >> 3;                 // 0..63 -> 2 pixels each

    const char* __restrict__ zc = (const char*)zbuf;
    const char* __restrict__ dc = (const char*)dists;
    const char* __restrict__ fc = (const char*)p2f;

    const int tile0 = blockIdx.x * TILES_PB;
    const bool nw10 = (wid < 3);             // wave's glds count: 10 else 9

    // ---- stage one tile: 75 x 1KB steps, round-robin over waves ----
    auto stage = [&](int tile, char* buf) {
        const size_t tb = (size_t)tile * ARR_B;
        #pragma unroll 1
        for (int s = wid; s < STEPS; s += WAVES) {       // wave-uniform
            const int a = s / 25;                        // 0..2
            const int j = s - a * 25;                    // 0..24
            const char* g = (a == 0) ? zc + tb : (a == 1) ? dc + tb : fc + tb;
            GLDS16(g + j * 1024 + lane * 16, buf + a * ARR_B + j * 1024);
        }
    };

    // ---- compute one tile from LDS (R5 dual-pixel team structure) ----
    auto compute = [&](int tile, const char* buf) {
        const float2* __restrict__ zl = (const float2*)(buf);
        const float2* __restrict__ dl = (const float2*)(buf + ARR_B);
        const int2*   __restrict__ fl = (const int2*)(buf + 2 * ARR_B);

        const int pA  = 2 * team;
        const int cbA = pA * 25;
        const int cbB = cbA + 25;
        const int a0 = cbA + q, a1 = cbA + q + 8, a2 = cbA + q + 16, a3 = cbA + 24;
        const int b0 = cbB + q, b1 = cbB + q + 8, b2 = cbB + q + 16, b3 = cbB + 24;

        const int2   fA0 = fl[a0], fA1 = fl[a1], fA2 = fl[a2], fA3 = fl[a3];
        const int2   fB0 = fl[b0], fB1 = fl[b1], fB2 = fl[b2], fB3 = fl[b3];
        const float2 zA0 = zl[a0], zA1 = zl[a1], zA2 = zl[a2], zA3 = zl[a3];
        const float2 zB0 = zl[b0], zB1 = zl[b1], zB2 = zl[b2], zB3 = zl[b3];
        const float2 dA0 = dl[a0], dA1 = dl[a1], dA2 = dl[a2], dA3 = dl[a3];
        const float2 dB0 = dl[b0], dB1 = dl[b1], dB2 = dl[b2], dB3 = dl[b3];

        const bool town = (q == 0);
        float mA, S1A, S2A, mB, S1B, S2B;
        pixel_blend(fA0, fA1, fA2, fA3, zA0, zA1, zA2, zA3,
                    dA0, dA1, dA2, dA3, town, mA, S1A, S2A);
        pixel_blend(fB0, fB1, fB2, fB3, zB0, zB1, zB2, zB3,
                    dB0, dB1, dB2, dB3, town, mB, S1B, S2B);

        if (q < 2) {
            const float m  = (q == 0) ? mA  : mB;
            const float s1 = (q == 0) ? S1A : S1B;
            const float s2 = (q == 0) ? S2A : S2B;
            const float delta = fmaxf(__expf((EPS - m) * INVG), EPS);
            out[(size_t)tile * TILE_PX + pA + q] =
                __fdividef(s2 + delta, s1 + delta);      // BG_BLUE = 1
        }
    };

    // ---- 2-deep pipeline with COUNTED vmcnt (never 0 mid-loop) ----
    // Per-wave vmem queue at the wait of iter i (oldest first):
    //   [stage(i): nw] [store(i-1): 1] [stage(i+1): nw]
    // In-order retirement => waiting to (nw+1) outstanding drains stage(i)
    // while leaving {store(i-1), stage(i+1)} in flight. Iter 0 has no store
    // (wait nw); last iter has nothing after stage (wait 1).
    stage(tile0, smem);

    #pragma unroll 1
    for (int i = 0; i < TILES_PB; ++i) {
        const char* cbuf = smem + (i & 1) * BUF_B;
        if (i + 1 < TILES_PB)
            stage(tile0 + i + 1, smem + ((i + 1) & 1) * BUF_B);

        if (i == 0)                { if (nw10) VMWAIT(10); else VMWAIT(9);  }
        else if (i + 1 < TILES_PB) { if (nw10) VMWAIT(11); else VMWAIT(10); }
        else                       { VMWAIT(1); }
        __builtin_amdgcn_sched_barrier(0);
        __builtin_amdgcn_s_barrier();            // all waves' portions landed
        __builtin_amdgcn_sched_barrier(0);

        compute(tile0 + i, cbuf);

        __builtin_amdgcn_sched_barrier(0);
        __builtin_amdgcn_s_barrier();            // buf free for stage(i+2)
        __builtin_amdgcn_sched_barrier(0);
    }
}

extern "C" void kernel_launch(void* const* d_in, const int* in_sizes, int n_in,
                              void* d_out, int out_size, void* d_ws, size_t ws_size,
                              hipStream_t stream) {
    const float* zbuf  = (const float*)d_in[0];
    const float* dists = (const float*)d_in[1];
    const int*   p2f   = (const int*)d_in[2];
    float* out = (float*)d_out;

    const int pixels = out_size;                       // 524288
    const int blocks = pixels / (TILE_PX * TILES_PB);  // 256 (exact)

    soft_depth_kernel<<<dim3(blocks), dim3(THREADS), 0, stream>>>(
        zbuf, dists, p2f, out);
}